// Round 5
// baseline (191.564 us; speedup 1.0000x reference)
//
#include <hip/hip_runtime.h>
#include <stdint.h>

// Problem constants
#define Bc 2
#define Sc 2048
#define Ec 1024
#define Hc 16
#define Dc 64
#define Mc (Bc*Sc)   // 4096 rows

typedef __attribute__((ext_vector_type(4))) float f32x4;
typedef __attribute__((ext_vector_type(8))) short bf16x8v;
typedef __attribute__((ext_vector_type(4))) short bf16x4v;

// 0.125 * log2(e): folded into Q at the GEMM epilogue -> scores exit QK^T in exp2 domain
#define SCL 0.1803368801f

__device__ __forceinline__ unsigned short f2bf(float f){
  unsigned int u = __float_as_uint(f);
  u += 0x7FFFu + ((u >> 16) & 1u);     // RNE
  return (unsigned short)(u >> 16);
}

// packed RNE f32x2 -> bf16x2 (gfx950 VOP3); a -> low16, b -> high16
__device__ __forceinline__ unsigned int cvt_pk_bf16(float a, float b){
  unsigned int d;
  asm("v_cvt_pk_bf16_f32 %0, %1, %2" : "=v"(d) : "v"(a), "v"(b));
  return d;
}

// raw v_exp_f32 (2^x); skips the OCML wrapper's edge-case VALU ops
__device__ __forceinline__ float fast_exp2(float x){
  float r;
  asm("v_exp_f32 %0, %1" : "=v"(r) : "v"(x));
  return r;
}

#define GLDS(src, dst) __builtin_amdgcn_global_load_lds( \
    (const __attribute__((address_space(1))) void*)(src), \
    (__attribute__((address_space(3))) void*)(dst), 16, 0, 0)

// -------- fused prep: X fp32->bf16 (blocks 0..4095) + W->WT bf16 (blocks 4096..5119) ----
__global__ __launch_bounds__(256) void k_prep(const float* __restrict__ X,
                                              unsigned short* __restrict__ Xb,
                                              const float* __restrict__ W0, const float* __restrict__ W1,
                                              const float* __restrict__ W2, const float* __restrict__ W3,
                                              unsigned short* __restrict__ WT4){
  __shared__ float st[64][65];
  int bx = blockIdx.x, t = threadIdx.x;
  if (bx < 4096){
    int i = bx*256 + t;
    float4 v = ((const float4*)X)[i];
    ushort4 o;
    o.x = f2bf(v.x); o.y = f2bf(v.y); o.z = f2bf(v.z); o.w = f2bf(v.w);
    ((ushort4*)Xb)[i] = o;
  } else {
    int id = bx - 4096;
    int z = id >> 8, rem = id & 255;
    int k0 = (rem >> 4)*64, n0 = (rem & 15)*64;
    const float* W = (z==0)?W0 : (z==1)?W1 : (z==2)?W2 : W3;
    unsigned short* o = WT4 + (size_t)z * Ec * Ec;
    #pragma unroll
    for (int i=0;i<16;i++){ int lin=i*256+t; int r=lin>>6, c=lin&63;
      st[r][c] = W[(size_t)(k0+r)*Ec + n0+c]; }
    __syncthreads();
    #pragma unroll
    for (int i=0;i<16;i++){ int lin=i*256+t; int nn=lin>>6, kk=lin&63;
      o[(size_t)(n0+nn)*Ec + k0+kk] = f2bf(st[kk][nn]); }
  }
}

// ------------- FUSED QKV GEMM: BK=32, paired-line swizzle, 40 KB LDS -> 4 blocks/CU -------------
// BM=128, BN=64. Outputs: z=0 Q*SCL [B][H][S][D], z=1 K [B][H][S][D], z=2 V^T [B][H][D][S].
// LDS layout (per tile): "line" = 2 consecutive rows (128 B); logical slot within a line
// p = (row&1)*4 + kc (kc = 16B k-chunk, 4 per row); physical slot = p ^ (line&7).
// Bank check for frag reads (16 lanes, rows base+m16, base%16==0, fixed kc=quad):
// bank = ((u*4+quad)^v)*4 with u=m16&1, v=m16>>1 -> each bank hit exactly 2x = free (m136).
// Staging writes the same involution from the global side; GLDS destinations stay linear.
__global__ __launch_bounds__(256,4) void k_qkv(const unsigned short* __restrict__ A,
                                               const unsigned short* __restrict__ WT4,
                                               const float* __restrict__ bq,
                                               const float* __restrict__ bk,
                                               const float* __restrict__ bv,
                                               unsigned short* __restrict__ QKV){
  __shared__ unsigned short sA[2][128*32];     // 8 KB per buf
  __shared__ unsigned short sB[2][3][64*32];   // 4 KB per slice
  int bm = blockIdx.y, bn = blockIdx.x;        // bn: 0..15 over N=1024
  int t = threadIdx.x, w = t>>6, lane = t&63, quad = lane>>4, m16 = lane&15;
  int wm = w>>1, wn = w&1;
  f32x4 acc[3][4][2];
  #pragma unroll
  for (int z=0;z<3;z++)
    #pragma unroll
    for (int i=0;i<4;i++)
      #pragma unroll
      for (int j=0;j<2;j++) acc[z][i][j] = (f32x4){0.f,0.f,0.f,0.f};

  auto stage = [&](int kt, int buf){
    #pragma unroll
    for (int i=0;i<2;i++){                     // A: 128x32 = 512 chunks, 2/thread
      int L = (w*2 + i)*64 + lane;
      int l = L>>3, s = L&7, p = s ^ (l&7);
      int row = 2*l + (p>>2), kc = p&3;
      GLDS(A + (size_t)(bm*128 + row)*Ec + kt*32 + kc*8, &sA[buf][0] + L*8);
    }
    #pragma unroll
    for (int z=0;z<3;z++){                     // each B slice: 64x32 = 256 chunks, 1/thread
      int L = w*64 + lane;
      int l = L>>3, s = L&7, p = s ^ (l&7);
      int row = 2*l + (p>>2), kc = p&3;
      GLDS(WT4 + (size_t)z*Ec*Ec + (size_t)(bn*64 + row)*Ec + kt*32 + kc*8,
           &sB[buf][z][0] + L*8);
    }
  };

  stage(0, 0);
  for (int kt=0; kt<Ec/32; ++kt){
    int cur = kt & 1;
    __syncthreads();
    if (kt+1 < Ec/32) stage(kt+1, cur^1);
    bf16x8v af[4];
    #pragma unroll
    for (int s=0;s<4;s++){
      int row = wm*64 + s*16 + m16;
      int l = row>>1, p = ((row&1)<<2) + quad;
      af[s] = *(const bf16x8v*)(&sA[cur][0] + l*64 + (p^(l&7))*8);
    }
    #pragma unroll
    for (int z=0;z<3;z++){
      bf16x8v bfr[2];
      #pragma unroll
      for (int sn=0;sn<2;sn++){
        int rowb = wn*32 + sn*16 + m16;
        int lb = rowb>>1, pb = ((rowb&1)<<2) + quad;
        bfr[sn] = *(const bf16x8v*)(&sB[cur][z][0] + lb*64 + (pb^(lb&7))*8);
      }
      #pragma unroll
      for (int sm=0;sm<4;sm++)
        #pragma unroll
        for (int sn=0;sn<2;sn++)
          acc[z][sm][sn] = __builtin_amdgcn_mfma_f32_16x16x32_bf16(af[sm], bfr[sn], acc[z][sm][sn], 0,0,0);
    }
  }
  // epilogue: C/D layout row = quad*4+r, col = lane&15
  #pragma unroll
  for (int z=0;z<3;z++){
    const float* bias = (z==0)?bq : (z==1)?bk : bv;
    unsigned short* Out = QKV + (size_t)z * (size_t)Mc * Ec;
    #pragma unroll
    for (int sm=0;sm<4;sm++){
      int row0 = bm*128 + wm*64 + sm*16 + quad*4;
      int bidx = row0 >> 11;
      #pragma unroll
      for (int sn=0;sn<2;sn++){
        int col = bn*64 + wn*32 + sn*16 + m16;
        float bb = bias[col];
        int h = col >> 6, d = col & 63;
        if (z == 2){
          int s0 = row0 & (Sc-1);
          ushort4 pk;
          pk.x = f2bf(acc[z][sm][sn][0] + bb);
          pk.y = f2bf(acc[z][sm][sn][1] + bb);
          pk.z = f2bf(acc[z][sm][sn][2] + bb);
          pk.w = f2bf(acc[z][sm][sn][3] + bb);
          *(ushort4*)(Out + (((size_t)bidx*Hc + h)*Dc + d)*Sc + s0) = pk;
        } else {
          float sc_ = (z==0) ? SCL : 1.0f;   // fold 0.125*log2e into Q
          #pragma unroll
          for (int r=0;r<4;r++){
            int s = (row0 + r) & (Sc-1);
            Out[(((size_t)bidx*Hc + h)*Sc + s)*Dc + d] = f2bf((acc[z][sm][sn][r] + bb)*sc_);
          }
        }
      }
    }
  }
}

// ------------- out-proj GEMM: BK=64 swizzled, dbuf, fp32 out [4096][1024] -------------
// LDS 48KB -> 3 blocks/CU; (256,3) keeps regalloc <= the 3-wave/EU budget.
__global__ __launch_bounds__(256,3) void k_gemm1(const unsigned short* __restrict__ A,
                                                 const unsigned short* __restrict__ WT,
                                                 const float* __restrict__ bias,
                                                 float* __restrict__ Out){
  __shared__ unsigned short sA[2][128*64];
  __shared__ unsigned short sB[2][64*64];
  int bm = blockIdx.y, bn = blockIdx.x;
  int t = threadIdx.x, w = t>>6, lane = t&63, quad = lane>>4, m16 = lane&15;
  int wm = w>>1, wn = w&1, sw = m16 & 7;
  f32x4 acc[4][2];
  #pragma unroll
  for (int i=0;i<4;i++)
    #pragma unroll
    for (int j=0;j<2;j++) acc[i][j] = (f32x4){0.f,0.f,0.f,0.f};

  auto stage = [&](int kt, int buf){
    #pragma unroll
    for (int i=0;i<4;i++){
      int cb = (w*4 + i)*64;
      int L = cb + lane;
      int row = L>>3, c = (L&7) ^ (row&7);
      GLDS(A + (size_t)(bm*128 + row)*Ec + kt*64 + c*8, &sA[buf][0] + cb*8);
    }
    #pragma unroll
    for (int i=0;i<2;i++){
      int cb = (w*2 + i)*64;
      int L = cb + lane;
      int row = L>>3, c = (L&7) ^ (row&7);
      GLDS(WT + (size_t)(bn*64 + row)*Ec + kt*64 + c*8, &sB[buf][0] + cb*8);
    }
  };

  stage(0, 0);
  for (int kt=0; kt<Ec/64; ++kt){
    int cur = kt & 1;
    __syncthreads();
    if (kt+1 < Ec/64) stage(kt+1, cur^1);
    bf16x8v af[4][2], bfr[2][2];
    #pragma unroll
    for (int s=0;s<4;s++){
      int row = wm*64 + s*16 + m16;
      af[s][0] = *(const bf16x8v*)(&sA[cur][0] + row*64 + ((quad  )^sw)*8);
      af[s][1] = *(const bf16x8v*)(&sA[cur][0] + row*64 + ((quad+4)^sw)*8);
    }
    #pragma unroll
    for (int sn=0;sn<2;sn++){
      int rowb = wn*32 + sn*16 + m16;
      bfr[sn][0] = *(const bf16x8v*)(&sB[cur][0] + rowb*64 + ((quad  )^sw)*8);
      bfr[sn][1] = *(const bf16x8v*)(&sB[cur][0] + rowb*64 + ((quad+4)^sw)*8);
    }
    #pragma unroll
    for (int sm=0;sm<4;sm++)
      #pragma unroll
      for (int sn=0;sn<2;sn++){
        acc[sm][sn] = __builtin_amdgcn_mfma_f32_16x16x32_bf16(af[sm][0], bfr[sn][0], acc[sm][sn], 0,0,0);
        acc[sm][sn] = __builtin_amdgcn_mfma_f32_16x16x32_bf16(af[sm][1], bfr[sn][1], acc[sm][sn], 0,0,0);
      }
  }
  #pragma unroll
  for (int sm=0;sm<4;sm++){
    int row0 = bm*128 + wm*64 + sm*16 + quad*4;
    #pragma unroll
    for (int sn=0;sn<2;sn++){
      int col = bn*64 + wn*32 + sn*16 + m16;
      float bb = bias[col];
      #pragma unroll
      for (int r=0;r<4;r++)
        Out[(size_t)(row0+r)*Ec + col] = acc[sm][sn][r] + bb;
    }
  }
}

// ------------- flash attention: P stays in registers via K=16 PV MFMAs ----------
// QK^T (K=32, swapped operands) leaves S^T in C-layout: lane(quad,m16) reg r holds
// P^T[j=sm*16+quad*4+r][q=m16]. The 16x16x16 MFMA A-layout is A[i=lane&15][k=quad*4+e]
// -- identical granularity -> pack sc[sm] with 2 cvt_pk and it IS the A-frag for
// j-block sm. No LDS round-trip, no cross-lane ops. C-layout of K16 outputs matches
// the old epilogue (q=quad*4+r, d=m16) exactly.
__device__ __forceinline__ void attn_tile(const unsigned short* sK, const unsigned short* sVT,
                                          bf16x8v qf0, bf16x8v qf1,
                                          bf16x4v ones4, f32x4& li, f32x4* Oa,
                                          int kbase, int qw, int quad, int m16){
  int sw = m16 & 7;
  // S^T[j][q] = sum_d K[j][d] Q'[q][d]; C-layout: j=kbase+sm*16+quad*4+r, q=qw+m16
  f32x4 sc[4];
  #pragma unroll
  for (int sm=0;sm<4;sm++){
    int row = sm*16 + m16;
    bf16x8v kf0 = *(const bf16x8v*)(sK + row*64 + ((quad  )^sw)*8);
    bf16x8v kf1 = *(const bf16x8v*)(sK + row*64 + ((quad+4)^sw)*8);
    f32x4 a = (f32x4){0.f,0.f,0.f,0.f};
    a = __builtin_amdgcn_mfma_f32_16x16x32_bf16(kf0, qf0, a, 0,0,0);
    a = __builtin_amdgcn_mfma_f32_16x16x32_bf16(kf1, qf1, a, 0,0,0);
    sc[sm] = a;
  }
  // p = exp2(s); zero masked entries (diagonal tiles only)
  if (kbase + 63 > qw){
    #pragma unroll
    for (int sm=0;sm<4;sm++)
      #pragma unroll
      for (int r=0;r<4;r++){
        int kg = kbase + sm*16 + quad*4 + r;
        float p = fast_exp2(sc[sm][r]);
        sc[sm][r] = (kg <= qw + m16) ? p : 0.0f;
      }
  } else {
    #pragma unroll
    for (int sm=0;sm<4;sm++)
      #pragma unroll
      for (int r=0;r<4;r++) sc[sm][r] = fast_exp2(sc[sm][r]);
  }

  // in-lane A-frags for K=16 MFMAs: a16[sm] elem e = P[q=m16][j=sm*16+quad*4+e]
  bf16x4v a16[4];
  #pragma unroll
  for (int sm=0;sm<4;sm++){
    uint2 pk;
    pk.x = cvt_pk_bf16(sc[sm][0], sc[sm][1]);  // e0 low, e1 high
    pk.y = cvt_pk_bf16(sc[sm][2], sc[sm][3]);  // e2 low, e3 high
    a16[sm] = __builtin_bit_cast(bf16x4v, pk);
  }

  // li[q] += sum_j P[q][j] via ones-MFMA; C-layout row q=quad*4+r (matches O rows)
  #pragma unroll
  for (int sm=0;sm<4;sm++)
    li = __builtin_amdgcn_mfma_f32_16x16x16bf16_1k(a16[sm], ones4, li, 0,0,0);

  // O[q][d] += P·V ; B-frag B[k=j=quad*4+e][d=m16] = V^T[d=tt*16+m16][j=sm*16+quad*4+e]
  // from sVT row tt*16+m16: logical chunk sm*2+(quad>>1), half (quad&1) -> 8B swizzled read.
  #pragma unroll
  for (int tt=0;tt<4;tt++){
    int rowv = tt*16 + m16;
    #pragma unroll
    for (int sm=0;sm<4;sm++){
      uint2 vv = *(const uint2*)(sVT + rowv*64 + (((sm*2 + (quad>>1))^sw)*8) + (quad&1)*4);
      Oa[tt] = __builtin_amdgcn_mfma_f32_16x16x16bf16_1k(a16[sm], __builtin_bit_cast(bf16x4v, vv), Oa[tt], 0,0,0);
    }
  }
}

// grid (32, 32) = 1024 blocks, 32 KB LDS -> up to 5 blocks/CU (VGPR permitting).
// (qt, bh) mapping (proven in round 2):
//  * XCD pinning: bh ≡ bid (mod 8) -> 4 heads/XCD -> K/V set 2MB < 4MB L2.
//  * balance: resident quartets get qt = {a, 15-a, 16+a, 31-a}, work sum 62 = const.
__global__ __launch_bounds__(256,4) void k_attn(const unsigned short* __restrict__ Qb,
                                                const unsigned short* __restrict__ Kb,
                                                const unsigned short* __restrict__ VTb,
                                                unsigned short* __restrict__ Ob){
  __shared__ unsigned short sK [2][64*64]; // [j][d], 16B chunks XOR-swizzled by row&7
  __shared__ unsigned short sVT[2][64*64]; // [d][j], same swizzle
  int bid = (int)blockIdx.x + 32*(int)blockIdx.y;
  int g = bid >> 3;
  int h3 = g >> 2;                          // 0..31
  int qt = (h3 & 8) ? (h3 ^ 7) : h3;        // balance involution
  int bh = (bid & 7) + ((g & 3) << 3);      // head pinned to XCD = bid%8
  size_t base = (size_t)bh * Sc * Dc;
  const unsigned short* Q  = Qb  + base;
  const unsigned short* K  = Kb  + base;
  const unsigned short* VT = VTb + base;   // [d][s]
  int t = threadIdx.x, w = t>>6, lane = t&63, quad = lane>>4, m16 = lane&15;
  int qw = qt*64 + w*16;

  bf16x8v q0 = *(const bf16x8v*)(Q + (size_t)(qw + m16)*Dc + quad*8);
  bf16x8v q1 = *(const bf16x8v*)(Q + (size_t)(qw + m16)*Dc + 32 + quad*8);

  bf16x4v ones4;
  #pragma unroll
  for (int i=0;i<4;i++) ones4[i] = (short)0x3F80;   // bf16 1.0

  f32x4 Oa[4];
  #pragma unroll
  for (int i=0;i<4;i++) Oa[i] = (f32x4){0.f,0.f,0.f,0.f};
  f32x4 li = (f32x4){0.f,0.f,0.f,0.f};

  auto stage = [&](int kt, int buf){
    int kbase = kt*64;
    #pragma unroll
    for (int i=0;i<2;i++){
      int cb = (w*2 + i)*64;              // wave-uniform chunk base
      int L = cb + lane;
      int row = L>>3, p = L&7, c = p ^ (row&7);
      GLDS(K  + (size_t)(kbase+row)*Dc + c*8,        &sK[buf][0]  + cb*8);
      GLDS(VT + (size_t)row*Sc + kbase + c*8,        &sVT[buf][0] + cb*8);
    }
  };

  // pipelined: stage(kt+1) issues right after the barrier publishing stage(kt);
  // the DMA flies under the whole compute tile. One barrier per tile.
  stage(0, 0);
  for (int kt=0; kt<=qt; ++kt){
    int cur = kt & 1;
    __syncthreads();
    if (kt < qt) stage(kt+1, cur^1);
    attn_tile(&sK[cur][0], &sVT[cur][0], q0, q1, ones4, li, Oa, kt*64, qw, quad, m16);
  }

  // epilogue: O rows s = qw+quad*4+r, cols e = h*64 + tt*16 + m16; li already per-row
  int b = bh >> 4, h = bh & 15;
  float iv[4];
  #pragma unroll
  for (int r=0;r<4;r++) iv[r] = 1.0f/li[r];
  #pragma unroll
  for (int tt=0;tt<4;tt++)
    #pragma unroll
    for (int r=0;r<4;r++){
      int e = h*64 + tt*16 + m16;
      int s = qw + quad*4 + r;
      Ob[((size_t)b*Sc + s)*Ec + e] = f2bf(Oa[tt][r]*iv[r]);
    }
}

extern "C" void kernel_launch(void* const* d_in, const int* in_sizes, int n_in,
                              void* d_out, int out_size, void* d_ws, size_t ws_size,
                              hipStream_t stream){
  const float* X  = (const float*)d_in[0];
  const float* Wq = (const float*)d_in[1];
  const float* bq = (const float*)d_in[2];
  const float* Wk = (const float*)d_in[3];
  const float* bk = (const float*)d_in[4];
  const float* Wv = (const float*)d_in[5];
  const float* bv = (const float*)d_in[6];
  const float* Wo = (const float*)d_in[7];
  const float* bo = (const float*)d_in[8];

  uint8_t* ws = (uint8_t*)d_ws;
  unsigned short* Xb  = (unsigned short*)(ws);                    // 8 MB
  unsigned short* WT4 = (unsigned short*)(ws + (size_t)(8u<<20)); // 8 MB (WqT,WkT,WvT,WoT)
  unsigned short* QKV = (unsigned short*)(ws + (size_t)(16u<<20));// 24 MB (Q,K,V^T)
  unsigned short* ATT = (unsigned short*)(ws + (size_t)(40u<<20));// 8 MB

  k_prep<<<dim3(5120), 256, 0, stream>>>(X, Xb, Wq, Wk, Wv, Wo, WT4);
  k_qkv<<<dim3(16,32), 256, 0, stream>>>(Xb, WT4, bq, bk, bv, QKV);
  k_attn<<<dim3(32,32), 256, 0, stream>>>(QKV, QKV + (size_t)Mc*Ec, QKV + 2*(size_t)Mc*Ec, ATT);
  k_gemm1<<<dim3(16,32), 256, 0, stream>>>(ATT, WT4 + (size_t)3*Ec*Ec, bo, (float*)d_out);
}

// Round 6
// 169.648 us; speedup vs baseline: 1.1292x; 1.1292x over previous
//
#include <hip/hip_runtime.h>
#include <stdint.h>

// Problem constants
#define Bc 2
#define Sc 2048
#define Ec 1024
#define Hc 16
#define Dc 64
#define Mc (Bc*Sc)   // 4096 rows

typedef __attribute__((ext_vector_type(4))) float f32x4;
typedef __attribute__((ext_vector_type(8))) short bf16x8v;
typedef __attribute__((ext_vector_type(4))) short bf16x4v;

// 0.125 * log2(e): folded into Q at the GEMM epilogue -> scores exit QK^T in exp2 domain
#define SCL 0.1803368801f

__device__ __forceinline__ unsigned short f2bf(float f){
  unsigned int u = __float_as_uint(f);
  u += 0x7FFFu + ((u >> 16) & 1u);     // RNE
  return (unsigned short)(u >> 16);
}

// packed RNE f32x2 -> bf16x2 (gfx950 VOP3); a -> low16, b -> high16
__device__ __forceinline__ unsigned int cvt_pk_bf16(float a, float b){
  unsigned int d;
  asm("v_cvt_pk_bf16_f32 %0, %1, %2" : "=v"(d) : "v"(a), "v"(b));
  return d;
}

// raw v_exp_f32 (2^x); skips the OCML wrapper's edge-case VALU ops
__device__ __forceinline__ float fast_exp2(float x){
  float r;
  asm("v_exp_f32 %0, %1" : "=v"(r) : "v"(x));
  return r;
}

#define GLDS(src, dst) __builtin_amdgcn_global_load_lds( \
    (const __attribute__((address_space(1))) void*)(src), \
    (__attribute__((address_space(3))) void*)(dst), 16, 0, 0)

// counted vmem wait: steady-state phases never drain to 0 (T4)
#define VMCNT(n) do { asm volatile("s_waitcnt vmcnt(" #n ")" ::: "memory"); \
                      __builtin_amdgcn_sched_barrier(0); } while(0)
#define BARRIER() do { __builtin_amdgcn_s_barrier(); \
                       __builtin_amdgcn_sched_barrier(0); } while(0)

// -------- fused prep: X fp32->bf16 (blocks 0..4095) + W->WT bf16 (blocks 4096..5119) ----
__global__ __launch_bounds__(256) void k_prep(const float* __restrict__ X,
                                              unsigned short* __restrict__ Xb,
                                              const float* __restrict__ W0, const float* __restrict__ W1,
                                              const float* __restrict__ W2, const float* __restrict__ W3,
                                              unsigned short* __restrict__ WT4){
  __shared__ float st[64][65];
  int bx = blockIdx.x, t = threadIdx.x;
  if (bx < 4096){
    int i = bx*256 + t;
    float4 v = ((const float4*)X)[i];
    ushort4 o;
    o.x = f2bf(v.x); o.y = f2bf(v.y); o.z = f2bf(v.z); o.w = f2bf(v.w);
    ((ushort4*)Xb)[i] = o;
  } else {
    int id = bx - 4096;
    int z = id >> 8, rem = id & 255;
    int k0 = (rem >> 4)*64, n0 = (rem & 15)*64;
    const float* W = (z==0)?W0 : (z==1)?W1 : (z==2)?W2 : W3;
    unsigned short* o = WT4 + (size_t)z * Ec * Ec;
    #pragma unroll
    for (int i=0;i<16;i++){ int lin=i*256+t; int r=lin>>6, c=lin&63;
      st[r][c] = W[(size_t)(k0+r)*Ec + n0+c]; }
    __syncthreads();
    #pragma unroll
    for (int i=0;i<16;i++){ int lin=i*256+t; int nn=lin>>6, kk=lin&63;
      o[(size_t)(n0+nn)*Ec + k0+kk] = f2bf(st[kk][nn]); }
  }
}

// ------------- FUSED QKV GEMM: BK=64 (XOR-swizzled LDS), depth-2 counted-vmcnt pipeline ---------
// BM=128, BN=64. Outputs: z=0 Q*SCL [B][H][S][D], z=1 K [B][H][S][D], z=2 V^T [B][H][D][S].
// Pipeline: stage(kt) waited via vmcnt(10) (its 10 loads/wave are the oldest; stage(kt+1)'s
// 10 stay in flight); raw s_barrier (no compiler vmcnt(0) drain); compute; barrier;
// stage(kt+2) into the buffer just consumed. Tail iteration peels to vmcnt(0).
__global__ __launch_bounds__(256,2) void k_qkv(const unsigned short* __restrict__ A,
                                               const unsigned short* __restrict__ WT4,
                                               const float* __restrict__ bq,
                                               const float* __restrict__ bk,
                                               const float* __restrict__ bv,
                                               unsigned short* __restrict__ QKV){
  __shared__ unsigned short sA[2][128*64];     // 16 KB per buf, swizzled: slot p holds chunk p^(row&7)
  __shared__ unsigned short sB[2][3][64*64];   // 8 KB per slice
  int bm = blockIdx.y, bn = blockIdx.x;        // bn: 0..15 over N=1024
  int t = threadIdx.x, w = t>>6, lane = t&63, quad = lane>>4, m16 = lane&15;
  int wm = w>>1, wn = w&1, sw = m16 & 7;
  f32x4 acc[3][4][2];
  #pragma unroll
  for (int z=0;z<3;z++)
    #pragma unroll
    for (int i=0;i<4;i++)
      #pragma unroll
      for (int j=0;j<2;j++) acc[z][i][j] = (f32x4){0.f,0.f,0.f,0.f};

  auto stage = [&](int kt, int buf){
    #pragma unroll
    for (int i=0;i<4;i++){                     // A: 128x64 = 1024 chunks, 4/thread
      int cb = (w*4 + i)*64;
      int L = cb + lane;
      int row = L>>3, c = (L&7) ^ (row&7);
      GLDS(A + (size_t)(bm*128 + row)*Ec + kt*64 + c*8, &sA[buf][0] + cb*8);
    }
    #pragma unroll
    for (int z=0;z<3;z++)
      #pragma unroll
      for (int i=0;i<2;i++){                   // each B slice: 64x64 = 512 chunks, 2/thread
        int cb = (w*2 + i)*64;
        int L = cb + lane;
        int row = L>>3, c = (L&7) ^ (row&7);
        GLDS(WT4 + (size_t)z*Ec*Ec + (size_t)(bn*64 + row)*Ec + kt*64 + c*8,
             &sB[buf][z][0] + cb*8);
      }
  };

  stage(0, 0);
  stage(1, 1);
  for (int kt=0; kt<Ec/64; ++kt){
    int cur = kt & 1;
    if (kt < Ec/64 - 1) VMCNT(10);        // stage(kt) landed; stage(kt+1) still flying
    else                VMCNT(0);         // tail: only stage(NT-1) outstanding
    BARRIER();
    bf16x8v af[4][2];
    #pragma unroll
    for (int s=0;s<4;s++){
      int row = wm*64 + s*16 + m16;
      af[s][0] = *(const bf16x8v*)(&sA[cur][0] + row*64 + ((quad  )^sw)*8);
      af[s][1] = *(const bf16x8v*)(&sA[cur][0] + row*64 + ((quad+4)^sw)*8);
    }
    #pragma unroll
    for (int z=0;z<3;z++){
      bf16x8v bfr[2][2];
      #pragma unroll
      for (int sn=0;sn<2;sn++){
        int rowb = wn*32 + sn*16 + m16;
        bfr[sn][0] = *(const bf16x8v*)(&sB[cur][z][0] + rowb*64 + ((quad  )^sw)*8);
        bfr[sn][1] = *(const bf16x8v*)(&sB[cur][z][0] + rowb*64 + ((quad+4)^sw)*8);
      }
      #pragma unroll
      for (int sm=0;sm<4;sm++)
        #pragma unroll
        for (int sn=0;sn<2;sn++){
          acc[z][sm][sn] = __builtin_amdgcn_mfma_f32_16x16x32_bf16(af[sm][0], bfr[sn][0], acc[z][sm][sn], 0,0,0);
          acc[z][sm][sn] = __builtin_amdgcn_mfma_f32_16x16x32_bf16(af[sm][1], bfr[sn][1], acc[z][sm][sn], 0,0,0);
        }
    }
    BARRIER();                            // all waves done reading buf cur
    if (kt+2 < Ec/64) stage(kt+2, cur);   // overwrite it with tile kt+2
  }
  // epilogue: C/D layout row = quad*4+r, col = lane&15
  #pragma unroll
  for (int z=0;z<3;z++){
    const float* bias = (z==0)?bq : (z==1)?bk : bv;
    unsigned short* Out = QKV + (size_t)z * (size_t)Mc * Ec;
    #pragma unroll
    for (int sm=0;sm<4;sm++){
      int row0 = bm*128 + wm*64 + sm*16 + quad*4;
      int bidx = row0 >> 11;
      #pragma unroll
      for (int sn=0;sn<2;sn++){
        int col = bn*64 + wn*32 + sn*16 + m16;
        float bb = bias[col];
        int h = col >> 6, d = col & 63;
        if (z == 2){
          int s0 = row0 & (Sc-1);
          ushort4 pk;
          pk.x = f2bf(acc[z][sm][sn][0] + bb);
          pk.y = f2bf(acc[z][sm][sn][1] + bb);
          pk.z = f2bf(acc[z][sm][sn][2] + bb);
          pk.w = f2bf(acc[z][sm][sn][3] + bb);
          *(ushort4*)(Out + (((size_t)bidx*Hc + h)*Dc + d)*Sc + s0) = pk;
        } else {
          float sc_ = (z==0) ? SCL : 1.0f;   // fold 0.125*log2e into Q
          #pragma unroll
          for (int r=0;r<4;r++){
            int s = (row0 + r) & (Sc-1);
            Out[(((size_t)bidx*Hc + h)*Sc + s)*Dc + d] = f2bf((acc[z][sm][sn][r] + bb)*sc_);
          }
        }
      }
    }
  }
}

// ------------- out-proj GEMM: BK=64 swizzled, depth-2 counted-vmcnt, fp32 out [4096][1024] ------
__global__ __launch_bounds__(256,3) void k_gemm1(const unsigned short* __restrict__ A,
                                                 const unsigned short* __restrict__ WT,
                                                 const float* __restrict__ bias,
                                                 float* __restrict__ Out){
  __shared__ unsigned short sA[2][128*64];
  __shared__ unsigned short sB[2][64*64];
  int bm = blockIdx.y, bn = blockIdx.x;
  int t = threadIdx.x, w = t>>6, lane = t&63, quad = lane>>4, m16 = lane&15;
  int wm = w>>1, wn = w&1, sw = m16 & 7;
  f32x4 acc[4][2];
  #pragma unroll
  for (int i=0;i<4;i++)
    #pragma unroll
    for (int j=0;j<2;j++) acc[i][j] = (f32x4){0.f,0.f,0.f,0.f};

  auto stage = [&](int kt, int buf){
    #pragma unroll
    for (int i=0;i<4;i++){
      int cb = (w*4 + i)*64;
      int L = cb + lane;
      int row = L>>3, c = (L&7) ^ (row&7);
      GLDS(A + (size_t)(bm*128 + row)*Ec + kt*64 + c*8, &sA[buf][0] + cb*8);
    }
    #pragma unroll
    for (int i=0;i<2;i++){
      int cb = (w*2 + i)*64;
      int L = cb + lane;
      int row = L>>3, c = (L&7) ^ (row&7);
      GLDS(WT + (size_t)(bn*64 + row)*Ec + kt*64 + c*8, &sB[buf][0] + cb*8);
    }
  };

  stage(0, 0);
  stage(1, 1);
  for (int kt=0; kt<Ec/64; ++kt){
    int cur = kt & 1;
    if (kt < Ec/64 - 1) VMCNT(6);
    else                VMCNT(0);
    BARRIER();
    bf16x8v af[4][2], bfr[2][2];
    #pragma unroll
    for (int s=0;s<4;s++){
      int row = wm*64 + s*16 + m16;
      af[s][0] = *(const bf16x8v*)(&sA[cur][0] + row*64 + ((quad  )^sw)*8);
      af[s][1] = *(const bf16x8v*)(&sA[cur][0] + row*64 + ((quad+4)^sw)*8);
    }
    #pragma unroll
    for (int sn=0;sn<2;sn++){
      int rowb = wn*32 + sn*16 + m16;
      bfr[sn][0] = *(const bf16x8v*)(&sB[cur][0] + rowb*64 + ((quad  )^sw)*8);
      bfr[sn][1] = *(const bf16x8v*)(&sB[cur][0] + rowb*64 + ((quad+4)^sw)*8);
    }
    #pragma unroll
    for (int sm=0;sm<4;sm++)
      #pragma unroll
      for (int sn=0;sn<2;sn++){
        acc[sm][sn] = __builtin_amdgcn_mfma_f32_16x16x32_bf16(af[sm][0], bfr[sn][0], acc[sm][sn], 0,0,0);
        acc[sm][sn] = __builtin_amdgcn_mfma_f32_16x16x32_bf16(af[sm][1], bfr[sn][1], acc[sm][sn], 0,0,0);
      }
    BARRIER();
    if (kt+2 < Ec/64) stage(kt+2, cur);
  }
  #pragma unroll
  for (int sm=0;sm<4;sm++){
    int row0 = bm*128 + wm*64 + sm*16 + quad*4;
    #pragma unroll
    for (int sn=0;sn<2;sn++){
      int col = bn*64 + wn*32 + sn*16 + m16;
      float bb = bias[col];
      #pragma unroll
      for (int r=0;r<4;r++)
        Out[(size_t)(row0+r)*Ec + col] = acc[sm][sn][r] + bb;
    }
  }
}

// ------------- flash attention: P stays in registers via K=16 PV MFMAs (proven r4) ----------
__device__ __forceinline__ void attn_tile(const unsigned short* sK, const unsigned short* sVT,
                                          bf16x8v qf0, bf16x8v qf1,
                                          bf16x4v ones4, f32x4& li, f32x4* Oa,
                                          int kbase, int qw, int quad, int m16){
  int sw = m16 & 7;
  // S^T[j][q] = sum_d K[j][d] Q'[q][d]; C-layout: j=kbase+sm*16+quad*4+r, q=qw+m16
  f32x4 sc[4];
  #pragma unroll
  for (int sm=0;sm<4;sm++){
    int row = sm*16 + m16;
    bf16x8v kf0 = *(const bf16x8v*)(sK + row*64 + ((quad  )^sw)*8);
    bf16x8v kf1 = *(const bf16x8v*)(sK + row*64 + ((quad+4)^sw)*8);
    f32x4 a = (f32x4){0.f,0.f,0.f,0.f};
    a = __builtin_amdgcn_mfma_f32_16x16x32_bf16(kf0, qf0, a, 0,0,0);
    a = __builtin_amdgcn_mfma_f32_16x16x32_bf16(kf1, qf1, a, 0,0,0);
    sc[sm] = a;
  }
  // p = exp2(s); zero masked entries (diagonal tiles only)
  if (kbase + 63 > qw){
    #pragma unroll
    for (int sm=0;sm<4;sm++)
      #pragma unroll
      for (int r=0;r<4;r++){
        int kg = kbase + sm*16 + quad*4 + r;
        float p = fast_exp2(sc[sm][r]);
        sc[sm][r] = (kg <= qw + m16) ? p : 0.0f;
      }
  } else {
    #pragma unroll
    for (int sm=0;sm<4;sm++)
      #pragma unroll
      for (int r=0;r<4;r++) sc[sm][r] = fast_exp2(sc[sm][r]);
  }

  // in-lane A-frags for K=16 MFMAs: a16[sm] elem e = P[q=m16][j=sm*16+quad*4+e]
  bf16x4v a16[4];
  #pragma unroll
  for (int sm=0;sm<4;sm++){
    uint2 pk;
    pk.x = cvt_pk_bf16(sc[sm][0], sc[sm][1]);  // e0 low, e1 high
    pk.y = cvt_pk_bf16(sc[sm][2], sc[sm][3]);  // e2 low, e3 high
    a16[sm] = __builtin_bit_cast(bf16x4v, pk);
  }

  // li[q] += sum_j P[q][j] via ones-MFMA; C-layout row q=quad*4+r (matches O rows)
  #pragma unroll
  for (int sm=0;sm<4;sm++)
    li = __builtin_amdgcn_mfma_f32_16x16x16bf16_1k(a16[sm], ones4, li, 0,0,0);

  // O[q][d] += P·V ; B-frag B[k=j=quad*4+e][d=m16] = V^T[d=tt*16+m16][j=sm*16+quad*4+e]
  #pragma unroll
  for (int tt=0;tt<4;tt++){
    int rowv = tt*16 + m16;
    #pragma unroll
    for (int sm=0;sm<4;sm++){
      uint2 vv = *(const uint2*)(sVT + rowv*64 + (((sm*2 + (quad>>1))^sw)*8) + (quad&1)*4);
      Oa[tt] = __builtin_amdgcn_mfma_f32_16x16x16bf16_1k(a16[sm], __builtin_bit_cast(bf16x4v, vv), Oa[tt], 0,0,0);
    }
  }
}

// grid (32, 32) = 1024 blocks. XCD pin + balance mapping proven in round 2.
__global__ __launch_bounds__(256,4) void k_attn(const unsigned short* __restrict__ Qb,
                                                const unsigned short* __restrict__ Kb,
                                                const unsigned short* __restrict__ VTb,
                                                unsigned short* __restrict__ Ob){
  __shared__ unsigned short sK [2][64*64]; // [j][d], 16B chunks XOR-swizzled by row&7
  __shared__ unsigned short sVT[2][64*64]; // [d][j], same swizzle
  int bid = (int)blockIdx.x + 32*(int)blockIdx.y;
  int g = bid >> 3;
  int h3 = g >> 2;                          // 0..31
  int qt = (h3 & 8) ? (h3 ^ 7) : h3;        // balance involution
  int bh = (bid & 7) + ((g & 3) << 3);      // head pinned to XCD = bid%8
  size_t base = (size_t)bh * Sc * Dc;
  const unsigned short* Q  = Qb  + base;
  const unsigned short* K  = Kb  + base;
  const unsigned short* VT = VTb + base;   // [d][s]
  int t = threadIdx.x, w = t>>6, lane = t&63, quad = lane>>4, m16 = lane&15;
  int qw = qt*64 + w*16;

  bf16x8v q0 = *(const bf16x8v*)(Q + (size_t)(qw + m16)*Dc + quad*8);
  bf16x8v q1 = *(const bf16x8v*)(Q + (size_t)(qw + m16)*Dc + 32 + quad*8);

  bf16x4v ones4;
  #pragma unroll
  for (int i=0;i<4;i++) ones4[i] = (short)0x3F80;   // bf16 1.0

  f32x4 Oa[4];
  #pragma unroll
  for (int i=0;i<4;i++) Oa[i] = (f32x4){0.f,0.f,0.f,0.f};
  f32x4 li = (f32x4){0.f,0.f,0.f,0.f};

  auto stage = [&](int kt, int buf){
    int kbase = kt*64;
    #pragma unroll
    for (int i=0;i<2;i++){
      int cb = (w*2 + i)*64;              // wave-uniform chunk base
      int L = cb + lane;
      int row = L>>3, p = L&7, c = p ^ (row&7);
      GLDS(K  + (size_t)(kbase+row)*Dc + c*8,        &sK[buf][0]  + cb*8);
      GLDS(VT + (size_t)row*Sc + kbase + c*8,        &sVT[buf][0] + cb*8);
    }
  };

  // pipelined: stage(kt+1) issues right after the barrier publishing stage(kt).
  stage(0, 0);
  for (int kt=0; kt<=qt; ++kt){
    int cur = kt & 1;
    __syncthreads();
    if (kt < qt) stage(kt+1, cur^1);
    attn_tile(&sK[cur][0], &sVT[cur][0], q0, q1, ones4, li, Oa, kt*64, qw, quad, m16);
  }

  // epilogue: O rows s = qw+quad*4+r, cols e = h*64 + tt*16 + m16; li already per-row
  int b = bh >> 4, h = bh & 15;
  float iv[4];
  #pragma unroll
  for (int r=0;r<4;r++) iv[r] = 1.0f/li[r];
  #pragma unroll
  for (int tt=0;tt<4;tt++)
    #pragma unroll
    for (int r=0;r<4;r++){
      int e = h*64 + tt*16 + m16;
      int s = qw + quad*4 + r;
      Ob[((size_t)b*Sc + s)*Ec + e] = f2bf(Oa[tt][r]*iv[r]);
    }
}

extern "C" void kernel_launch(void* const* d_in, const int* in_sizes, int n_in,
                              void* d_out, int out_size, void* d_ws, size_t ws_size,
                              hipStream_t stream){
  const float* X  = (const float*)d_in[0];
  const float* Wq = (const float*)d_in[1];
  const float* bq = (const float*)d_in[2];
  const float* Wk = (const float*)d_in[3];
  const float* bk = (const float*)d_in[4];
  const float* Wv = (const float*)d_in[5];
  const float* bv = (const float*)d_in[6];
  const float* Wo = (const float*)d_in[7];
  const float* bo = (const float*)d_in[8];

  uint8_t* ws = (uint8_t*)d_ws;
  unsigned short* Xb  = (unsigned short*)(ws);                    // 8 MB
  unsigned short* WT4 = (unsigned short*)(ws + (size_t)(8u<<20)); // 8 MB (WqT,WkT,WvT,WoT)
  unsigned short* QKV = (unsigned short*)(ws + (size_t)(16u<<20));// 24 MB (Q,K,V^T)
  unsigned short* ATT = (unsigned short*)(ws + (size_t)(40u<<20));// 8 MB

  k_prep<<<dim3(5120), 256, 0, stream>>>(X, Xb, Wq, Wk, Wv, Wo, WT4);
  k_qkv<<<dim3(16,32), 256, 0, stream>>>(Xb, WT4, bq, bk, bv, QKV);
  k_attn<<<dim3(32,32), 256, 0, stream>>>(QKV, QKV + (size_t)Mc*Ec, QKV + 2*(size_t)Mc*Ec, ATT);
  k_gemm1<<<dim3(16,32), 256, 0, stream>>>(ATT, WT4 + (size_t)3*Ec*Ec, bo, (float*)d_out);
}

// Round 7
// 168.619 us; speedup vs baseline: 1.1361x; 1.0061x over previous
//
#include <hip/hip_runtime.h>
#include <stdint.h>

// Problem constants
#define Bc 2
#define Sc 2048
#define Ec 1024
#define Hc 16
#define Dc 64
#define Mc (Bc*Sc)   // 4096 rows

typedef __attribute__((ext_vector_type(4))) float f32x4;
typedef __attribute__((ext_vector_type(8))) short bf16x8v;
typedef __attribute__((ext_vector_type(4))) short bf16x4v;

// 0.125 * log2(e): folded into Q at the GEMM epilogue -> scores exit QK^T in exp2 domain
#define SCL 0.1803368801f

__device__ __forceinline__ unsigned short f2bf(float f){
  unsigned int u = __float_as_uint(f);
  u += 0x7FFFu + ((u >> 16) & 1u);     // RNE
  return (unsigned short)(u >> 16);
}

// packed RNE f32x2 -> bf16x2 (gfx950 VOP3); a -> low16, b -> high16
__device__ __forceinline__ unsigned int cvt_pk_bf16(float a, float b){
  unsigned int d;
  asm("v_cvt_pk_bf16_f32 %0, %1, %2" : "=v"(d) : "v"(a), "v"(b));
  return d;
}

// raw v_exp_f32 (2^x); skips the OCML wrapper's edge-case VALU ops
__device__ __forceinline__ float fast_exp2(float x){
  float r;
  asm("v_exp_f32 %0, %1" : "=v"(r) : "v"(x));
  return r;
}

#define GLDS(src, dst) __builtin_amdgcn_global_load_lds( \
    (const __attribute__((address_space(1))) void*)(src), \
    (__attribute__((address_space(3))) void*)(dst), 16, 0, 0)

// counted vmem wait: steady-state phases never drain to 0 (T4)
#define VMCNT(n) do { asm volatile("s_waitcnt vmcnt(" #n ")" ::: "memory"); \
                      __builtin_amdgcn_sched_barrier(0); } while(0)
#define BARRIER() do { __builtin_amdgcn_s_barrier(); \
                       __builtin_amdgcn_sched_barrier(0); } while(0)

// -------- fused prep: X fp32->bf16 (blocks 0..4095) + W->WT bf16 (blocks 4096..5119) ----
__global__ __launch_bounds__(256) void k_prep(const float* __restrict__ X,
                                              unsigned short* __restrict__ Xb,
                                              const float* __restrict__ W0, const float* __restrict__ W1,
                                              const float* __restrict__ W2, const float* __restrict__ W3,
                                              unsigned short* __restrict__ WT4){
  __shared__ float st[64][65];
  int bx = blockIdx.x, t = threadIdx.x;
  if (bx < 4096){
    int i = bx*256 + t;
    float4 v = ((const float4*)X)[i];
    ushort4 o;
    o.x = f2bf(v.x); o.y = f2bf(v.y); o.z = f2bf(v.z); o.w = f2bf(v.w);
    ((ushort4*)Xb)[i] = o;
  } else {
    int id = bx - 4096;
    int z = id >> 8, rem = id & 255;
    int k0 = (rem >> 4)*64, n0 = (rem & 15)*64;
    const float* W = (z==0)?W0 : (z==1)?W1 : (z==2)?W2 : W3;
    unsigned short* o = WT4 + (size_t)z * Ec * Ec;
    #pragma unroll
    for (int i=0;i<16;i++){ int lin=i*256+t; int r=lin>>6, c=lin&63;
      st[r][c] = W[(size_t)(k0+r)*Ec + n0+c]; }
    __syncthreads();
    #pragma unroll
    for (int i=0;i<16;i++){ int lin=i*256+t; int nn=lin>>6, kk=lin&63;
      o[(size_t)(n0+nn)*Ec + k0+kk] = f2bf(st[kk][nn]); }
  }
}

// ------------- FUSED QKV GEMM: BK=64 (XOR-swizzled LDS), depth-2 counted-vmcnt pipeline ---------
// BM=128, BN=64. Outputs: z=0 Q*SCL [B][H][S][D], z=1 K [B][H][S][D], z=2 V^T [B][H][D][S].
// V^T is stored with 8B halves swapped within each 16B s-chunk on rows with (d&8):
// store col = s0 ^ ((d&8)?4:0). Consumed by k_attn's bank-conflict-free V-read.
__global__ __launch_bounds__(256,2) void k_qkv(const unsigned short* __restrict__ A,
                                               const unsigned short* __restrict__ WT4,
                                               const float* __restrict__ bq,
                                               const float* __restrict__ bk,
                                               const float* __restrict__ bv,
                                               unsigned short* __restrict__ QKV){
  __shared__ unsigned short sA[2][128*64];     // 16 KB per buf, swizzled: slot p holds chunk p^(row&7)
  __shared__ unsigned short sB[2][3][64*64];   // 8 KB per slice
  int bm = blockIdx.y, bn = blockIdx.x;        // bn: 0..15 over N=1024
  int t = threadIdx.x, w = t>>6, lane = t&63, quad = lane>>4, m16 = lane&15;
  int wm = w>>1, wn = w&1, sw = m16 & 7;
  f32x4 acc[3][4][2];
  #pragma unroll
  for (int z=0;z<3;z++)
    #pragma unroll
    for (int i=0;i<4;i++)
      #pragma unroll
      for (int j=0;j<2;j++) acc[z][i][j] = (f32x4){0.f,0.f,0.f,0.f};

  auto stage = [&](int kt, int buf){
    #pragma unroll
    for (int i=0;i<4;i++){                     // A: 128x64 = 1024 chunks, 4/thread
      int cb = (w*4 + i)*64;
      int L = cb + lane;
      int row = L>>3, c = (L&7) ^ (row&7);
      GLDS(A + (size_t)(bm*128 + row)*Ec + kt*64 + c*8, &sA[buf][0] + cb*8);
    }
    #pragma unroll
    for (int z=0;z<3;z++)
      #pragma unroll
      for (int i=0;i<2;i++){                   // each B slice: 64x64 = 512 chunks, 2/thread
        int cb = (w*2 + i)*64;
        int L = cb + lane;
        int row = L>>3, c = (L&7) ^ (row&7);
        GLDS(WT4 + (size_t)z*Ec*Ec + (size_t)(bn*64 + row)*Ec + kt*64 + c*8,
             &sB[buf][z][0] + cb*8);
      }
  };

  stage(0, 0);
  stage(1, 1);
  for (int kt=0; kt<Ec/64; ++kt){
    int cur = kt & 1;
    if (kt < Ec/64 - 1) VMCNT(10);        // stage(kt) landed; stage(kt+1) still flying
    else                VMCNT(0);         // tail: only stage(NT-1) outstanding
    BARRIER();
    bf16x8v af[4][2];
    #pragma unroll
    for (int s=0;s<4;s++){
      int row = wm*64 + s*16 + m16;
      af[s][0] = *(const bf16x8v*)(&sA[cur][0] + row*64 + ((quad  )^sw)*8);
      af[s][1] = *(const bf16x8v*)(&sA[cur][0] + row*64 + ((quad+4)^sw)*8);
    }
    #pragma unroll
    for (int z=0;z<3;z++){
      bf16x8v bfr[2][2];
      #pragma unroll
      for (int sn=0;sn<2;sn++){
        int rowb = wn*32 + sn*16 + m16;
        bfr[sn][0] = *(const bf16x8v*)(&sB[cur][z][0] + rowb*64 + ((quad  )^sw)*8);
        bfr[sn][1] = *(const bf16x8v*)(&sB[cur][z][0] + rowb*64 + ((quad+4)^sw)*8);
      }
      #pragma unroll
      for (int sm=0;sm<4;sm++)
        #pragma unroll
        for (int sn=0;sn<2;sn++){
          acc[z][sm][sn] = __builtin_amdgcn_mfma_f32_16x16x32_bf16(af[sm][0], bfr[sn][0], acc[z][sm][sn], 0,0,0);
          acc[z][sm][sn] = __builtin_amdgcn_mfma_f32_16x16x32_bf16(af[sm][1], bfr[sn][1], acc[z][sm][sn], 0,0,0);
        }
    }
    BARRIER();                            // all waves done reading buf cur
    if (kt+2 < Ec/64) stage(kt+2, cur);   // overwrite it with tile kt+2
  }
  // epilogue: C/D layout row = quad*4+r, col = lane&15
  #pragma unroll
  for (int z=0;z<3;z++){
    const float* bias = (z==0)?bq : (z==1)?bk : bv;
    unsigned short* Out = QKV + (size_t)z * (size_t)Mc * Ec;
    #pragma unroll
    for (int sm=0;sm<4;sm++){
      int row0 = bm*128 + wm*64 + sm*16 + quad*4;
      int bidx = row0 >> 11;
      #pragma unroll
      for (int sn=0;sn<2;sn++){
        int col = bn*64 + wn*32 + sn*16 + m16;
        float bb = bias[col];
        int h = col >> 6, d = col & 63;
        if (z == 2){
          int s0 = (row0 & (Sc-1)) ^ ((d & 8) ? 4 : 0);   // half-swap rows d&8 (bank fix)
          ushort4 pk;
          pk.x = f2bf(acc[z][sm][sn][0] + bb);
          pk.y = f2bf(acc[z][sm][sn][1] + bb);
          pk.z = f2bf(acc[z][sm][sn][2] + bb);
          pk.w = f2bf(acc[z][sm][sn][3] + bb);
          *(ushort4*)(Out + (((size_t)bidx*Hc + h)*Dc + d)*Sc + s0) = pk;
        } else {
          float sc_ = (z==0) ? SCL : 1.0f;   // fold 0.125*log2e into Q
          #pragma unroll
          for (int r=0;r<4;r++){
            int s = (row0 + r) & (Sc-1);
            Out[(((size_t)bidx*Hc + h)*Sc + s)*Dc + d] = f2bf((acc[z][sm][sn][r] + bb)*sc_);
          }
        }
      }
    }
  }
}

// ------------- out-proj GEMM: BK=64 swizzled, depth-2 counted-vmcnt, fp32 out [4096][1024] ------
__global__ __launch_bounds__(256,3) void k_gemm1(const unsigned short* __restrict__ A,
                                                 const unsigned short* __restrict__ WT,
                                                 const float* __restrict__ bias,
                                                 float* __restrict__ Out){
  __shared__ unsigned short sA[2][128*64];
  __shared__ unsigned short sB[2][64*64];
  int bm = blockIdx.y, bn = blockIdx.x;
  int t = threadIdx.x, w = t>>6, lane = t&63, quad = lane>>4, m16 = lane&15;
  int wm = w>>1, wn = w&1, sw = m16 & 7;
  f32x4 acc[4][2];
  #pragma unroll
  for (int i=0;i<4;i++)
    #pragma unroll
    for (int j=0;j<2;j++) acc[i][j] = (f32x4){0.f,0.f,0.f,0.f};

  auto stage = [&](int kt, int buf){
    #pragma unroll
    for (int i=0;i<4;i++){
      int cb = (w*4 + i)*64;
      int L = cb + lane;
      int row = L>>3, c = (L&7) ^ (row&7);
      GLDS(A + (size_t)(bm*128 + row)*Ec + kt*64 + c*8, &sA[buf][0] + cb*8);
    }
    #pragma unroll
    for (int i=0;i<2;i++){
      int cb = (w*2 + i)*64;
      int L = cb + lane;
      int row = L>>3, c = (L&7) ^ (row&7);
      GLDS(WT + (size_t)(bn*64 + row)*Ec + kt*64 + c*8, &sB[buf][0] + cb*8);
    }
  };

  stage(0, 0);
  stage(1, 1);
  for (int kt=0; kt<Ec/64; ++kt){
    int cur = kt & 1;
    if (kt < Ec/64 - 1) VMCNT(6);
    else                VMCNT(0);
    BARRIER();
    bf16x8v af[4][2], bfr[2][2];
    #pragma unroll
    for (int s=0;s<4;s++){
      int row = wm*64 + s*16 + m16;
      af[s][0] = *(const bf16x8v*)(&sA[cur][0] + row*64 + ((quad  )^sw)*8);
      af[s][1] = *(const bf16x8v*)(&sA[cur][0] + row*64 + ((quad+4)^sw)*8);
    }
    #pragma unroll
    for (int sn=0;sn<2;sn++){
      int rowb = wn*32 + sn*16 + m16;
      bfr[sn][0] = *(const bf16x8v*)(&sB[cur][0] + rowb*64 + ((quad  )^sw)*8);
      bfr[sn][1] = *(const bf16x8v*)(&sB[cur][0] + rowb*64 + ((quad+4)^sw)*8);
    }
    #pragma unroll
    for (int sm=0;sm<4;sm++)
      #pragma unroll
      for (int sn=0;sn<2;sn++){
        acc[sm][sn] = __builtin_amdgcn_mfma_f32_16x16x32_bf16(af[sm][0], bfr[sn][0], acc[sm][sn], 0,0,0);
        acc[sm][sn] = __builtin_amdgcn_mfma_f32_16x16x32_bf16(af[sm][1], bfr[sn][1], acc[sm][sn], 0,0,0);
      }
    BARRIER();
    if (kt+2 < Ec/64) stage(kt+2, cur);
  }
  #pragma unroll
  for (int sm=0;sm<4;sm++){
    int row0 = bm*128 + wm*64 + sm*16 + quad*4;
    #pragma unroll
    for (int sn=0;sn<2;sn++){
      int col = bn*64 + wn*32 + sn*16 + m16;
      float bb = bias[col];
      #pragma unroll
      for (int r=0;r<4;r++)
        Out[(size_t)(row0+r)*Ec + col] = acc[sm][sn][r] + bb;
    }
  }
}

// ------------- flash attention: P in registers via K=16 PV MFMAs; conflict-free V-reads ---------
// V^T rows with (d&8) have 8B halves pre-swapped (producer side), so the V-read half is
// (quad&1)^(m16>>3): within each 16-lane phase the 16 (chunk,half) pairs are distinct ->
// all 32 banks hit exactly once (was: half fixed per phase -> 16 banks x2 = +4 cyc/read).
__device__ __forceinline__ void attn_tile(const unsigned short* sK, const unsigned short* sVT,
                                          bf16x8v qf0, bf16x8v qf1,
                                          bf16x4v ones4, f32x4& li, f32x4* Oa,
                                          int kbase, int qw, int quad, int m16){
  int sw = m16 & 7;
  // S^T[j][q] = sum_d K[j][d] Q'[q][d]; C-layout: j=kbase+sm*16+quad*4+r, q=qw+m16
  f32x4 sc[4];
  #pragma unroll
  for (int sm=0;sm<4;sm++){
    int row = sm*16 + m16;
    bf16x8v kf0 = *(const bf16x8v*)(sK + row*64 + ((quad  )^sw)*8);
    bf16x8v kf1 = *(const bf16x8v*)(sK + row*64 + ((quad+4)^sw)*8);
    f32x4 a = (f32x4){0.f,0.f,0.f,0.f};
    a = __builtin_amdgcn_mfma_f32_16x16x32_bf16(kf0, qf0, a, 0,0,0);
    a = __builtin_amdgcn_mfma_f32_16x16x32_bf16(kf1, qf1, a, 0,0,0);
    sc[sm] = a;
  }
  // p = exp2(s); zero masked entries (diagonal tiles only)
  if (kbase + 63 > qw){
    #pragma unroll
    for (int sm=0;sm<4;sm++)
      #pragma unroll
      for (int r=0;r<4;r++){
        int kg = kbase + sm*16 + quad*4 + r;
        float p = fast_exp2(sc[sm][r]);
        sc[sm][r] = (kg <= qw + m16) ? p : 0.0f;
      }
  } else {
    #pragma unroll
    for (int sm=0;sm<4;sm++)
      #pragma unroll
      for (int r=0;r<4;r++) sc[sm][r] = fast_exp2(sc[sm][r]);
  }

  // in-lane A-frags for K=16 MFMAs: a16[sm] elem e = P[q=m16][j=sm*16+quad*4+e]
  bf16x4v a16[4];
  #pragma unroll
  for (int sm=0;sm<4;sm++){
    uint2 pk;
    pk.x = cvt_pk_bf16(sc[sm][0], sc[sm][1]);  // e0 low, e1 high
    pk.y = cvt_pk_bf16(sc[sm][2], sc[sm][3]);  // e2 low, e3 high
    a16[sm] = __builtin_bit_cast(bf16x4v, pk);
  }

  // li[q] += sum_j P[q][j] via ones-MFMA; C-layout row q=quad*4+r (matches O rows)
  #pragma unroll
  for (int sm=0;sm<4;sm++)
    li = __builtin_amdgcn_mfma_f32_16x16x16bf16_1k(a16[sm], ones4, li, 0,0,0);

  // O[q][d] += P·V ; B-frag B[k=j=quad*4+e][d=m16] = V^T[d=tt*16+m16][j=sm*16+quad*4+e]
  // half = (quad&1)^(m16>>3) matches the producer's d&8 half-swap (rowv bit3 = m16 bit3).
  int half = ((quad & 1) ^ (m16 >> 3)) * 4;
  #pragma unroll
  for (int tt=0;tt<4;tt++){
    int rowv = tt*16 + m16;
    #pragma unroll
    for (int sm=0;sm<4;sm++){
      uint2 vv = *(const uint2*)(sVT + rowv*64 + (((sm*2 + (quad>>1))^sw)*8) + half);
      Oa[tt] = __builtin_amdgcn_mfma_f32_16x16x16bf16_1k(a16[sm], __builtin_bit_cast(bf16x4v, vv), Oa[tt], 0,0,0);
    }
  }
}

// grid (32, 32) = 1024 blocks. XCD pin + balance mapping proven in round 2.
__global__ __launch_bounds__(256,4) void k_attn(const unsigned short* __restrict__ Qb,
                                                const unsigned short* __restrict__ Kb,
                                                const unsigned short* __restrict__ VTb,
                                                unsigned short* __restrict__ Ob){
  __shared__ unsigned short sK [2][64*64]; // [j][d], 16B chunks XOR-swizzled by row&7
  __shared__ unsigned short sVT[2][64*64]; // [d][j], same swizzle (+ producer half-swap on d&8)
  int bid = (int)blockIdx.x + 32*(int)blockIdx.y;
  int g = bid >> 3;
  int h3 = g >> 2;                          // 0..31
  int qt = (h3 & 8) ? (h3 ^ 7) : h3;        // balance involution
  int bh = (bid & 7) + ((g & 3) << 3);      // head pinned to XCD = bid%8
  size_t base = (size_t)bh * Sc * Dc;
  const unsigned short* Q  = Qb  + base;
  const unsigned short* K  = Kb  + base;
  const unsigned short* VT = VTb + base;   // [d][s]
  int t = threadIdx.x, w = t>>6, lane = t&63, quad = lane>>4, m16 = lane&15;
  int qw = qt*64 + w*16;

  bf16x8v q0 = *(const bf16x8v*)(Q + (size_t)(qw + m16)*Dc + quad*8);
  bf16x8v q1 = *(const bf16x8v*)(Q + (size_t)(qw + m16)*Dc + 32 + quad*8);

  bf16x4v ones4;
  #pragma unroll
  for (int i=0;i<4;i++) ones4[i] = (short)0x3F80;   // bf16 1.0

  f32x4 Oa[4];
  #pragma unroll
  for (int i=0;i<4;i++) Oa[i] = (f32x4){0.f,0.f,0.f,0.f};
  f32x4 li = (f32x4){0.f,0.f,0.f,0.f};

  auto stage = [&](int kt, int buf){
    int kbase = kt*64;
    #pragma unroll
    for (int i=0;i<2;i++){
      int cb = (w*2 + i)*64;              // wave-uniform chunk base
      int L = cb + lane;
      int row = L>>3, p = L&7, c = p ^ (row&7);
      GLDS(K  + (size_t)(kbase+row)*Dc + c*8,        &sK[buf][0]  + cb*8);
      GLDS(VT + (size_t)row*Sc + kbase + c*8,        &sVT[buf][0] + cb*8);
    }
  };

  // pipelined: stage(kt+1) issues right after the barrier publishing stage(kt).
  stage(0, 0);
  for (int kt=0; kt<=qt; ++kt){
    int cur = kt & 1;
    __syncthreads();
    if (kt < qt) stage(kt+1, cur^1);
    attn_tile(&sK[cur][0], &sVT[cur][0], q0, q1, ones4, li, Oa, kt*64, qw, quad, m16);
  }

  // epilogue: O rows s = qw+quad*4+r, cols e = h*64 + tt*16 + m16; li already per-row
  int b = bh >> 4, h = bh & 15;
  float iv[4];
  #pragma unroll
  for (int r=0;r<4;r++) iv[r] = 1.0f/li[r];
  #pragma unroll
  for (int tt=0;tt<4;tt++)
    #pragma unroll
    for (int r=0;r<4;r++){
      int e = h*64 + tt*16 + m16;
      int s = qw + quad*4 + r;
      Ob[((size_t)b*Sc + s)*Ec + e] = f2bf(Oa[tt][r]*iv[r]);
    }
}

extern "C" void kernel_launch(void* const* d_in, const int* in_sizes, int n_in,
                              void* d_out, int out_size, void* d_ws, size_t ws_size,
                              hipStream_t stream){
  const float* X  = (const float*)d_in[0];
  const float* Wq = (const float*)d_in[1];
  const float* bq = (const float*)d_in[2];
  const float* Wk = (const float*)d_in[3];
  const float* bk = (const float*)d_in[4];
  const float* Wv = (const float*)d_in[5];
  const float* bv = (const float*)d_in[6];
  const float* Wo = (const float*)d_in[7];
  const float* bo = (const float*)d_in[8];

  uint8_t* ws = (uint8_t*)d_ws;
  unsigned short* Xb  = (unsigned short*)(ws);                    // 8 MB
  unsigned short* WT4 = (unsigned short*)(ws + (size_t)(8u<<20)); // 8 MB (WqT,WkT,WvT,WoT)
  unsigned short* QKV = (unsigned short*)(ws + (size_t)(16u<<20));// 24 MB (Q,K,V^T)
  unsigned short* ATT = (unsigned short*)(ws + (size_t)(40u<<20));// 8 MB

  k_prep<<<dim3(5120), 256, 0, stream>>>(X, Xb, Wq, Wk, Wv, Wo, WT4);
  k_qkv<<<dim3(16,32), 256, 0, stream>>>(Xb, WT4, bq, bk, bv, QKV);
  k_attn<<<dim3(32,32), 256, 0, stream>>>(QKV, QKV + (size_t)Mc*Ec, QKV + 2*(size_t)Mc*Ec, ATT);
  k_gemm1<<<dim3(16,32), 256, 0, stream>>>(ATT, WT4 + (size_t)3*Ec*Ec, bo, (float*)d_out);
}